// Round 1
// baseline (2571.518 us; speedup 1.0000x reference)
//
#include <hip/hip_runtime.h>
#include <cstdint>

typedef unsigned short u16;
typedef unsigned int   u32;

#define D_MODEL 4096
#define HIDDEN  16384
#define NTOK    4096

typedef short bf16x8  __attribute__((ext_vector_type(8)));
typedef float floatx4 __attribute__((ext_vector_type(4)));

typedef __attribute__((address_space(1))) u32 gu32;
typedef __attribute__((address_space(3))) u32 lu32;

__device__ __forceinline__ void gl_lds16(const void* g, void* l) {
  __builtin_amdgcn_global_load_lds((gu32*)g, (lu32*)l, 16, 0, 0);
}

__device__ __forceinline__ u16 f32_bf16_rne(float f) {
  union { float f; u32 u; } c; c.f = f;
  u32 u = c.u;
  return (u16)((u + 0x7FFFu + ((u >> 16) & 1u)) >> 16);
}

__device__ __forceinline__ float gelu_tanh(float x) {
  // jax.nn.gelu approximate=True: 0.5*x*(1+tanh(sqrt(2/pi)*(x+0.044715*x^3)))
  float inner = 0.7978845608028654f * fmaf(0.044715f * x * x, x, x);
  return 0.5f * x * (1.0f + tanhf(inner));
}

// x fp32 -> bf16, vectorized 4-wide. Grid covers exactly NTOK*D_MODEL/4 threads.
__global__ void __launch_bounds__(256) cvt_f32_bf16(const float4* __restrict__ in,
                                                    ushort4* __restrict__ out) {
  int i = blockIdx.x * 256 + threadIdx.x;
  float4 v = in[i];
  ushort4 o;
  o.x = f32_bf16_rne(v.x);
  o.y = f32_bf16_rne(v.y);
  o.z = f32_bf16_rne(v.z);
  o.w = f32_bf16_rne(v.w);
  out[i] = o;
}

// C[M,N] = A[M,K] (bf16, row-major) * B[N,K]^T, B given as 4-bit packed + row scales.
// BM=BN=128, BK=32, 256 threads = 4 waves, each wave does 64x64 via 4x4 MFMA 16x16x32.
// LDS layout (both operands): [rowgroup g=row/16][kchunk c=k/8][row%16] of 16B chunks
//   -> offset in ushorts: g*512 + c*128 + (row%16)*8. Matches global_load_lds
//   (wave-uniform base + lane*16B with lane = c*16 + row%16) and is 2-way-conflict
//   free on ds_read_b128 fragment loads.
template <int K, int N, bool GELU>
__global__ void __launch_bounds__(256)
gemm_dq(const u16* __restrict__ A,   // [NTOK, K] bf16
        const int* __restrict__ Bp,  // [N, K/2] packed (1 byte per int32)
        const float* __restrict__ Bsc, // [N] scales
        u16* __restrict__ Cb,        // bf16 out (GELU path)
        float* __restrict__ Cf)      // fp32 out (final path)
{
  __shared__ __align__(16) u16 As[128 * 32];
  __shared__ __align__(16) u16 Bs[128 * 32];

  const int tid  = threadIdx.x;
  const int lane = tid & 63;
  const int wave = tid >> 6;      // 0..3
  const int quad = lane >> 4;     // 0..3
  const int l16  = lane & 15;
  const int wm = wave >> 1, wn = wave & 1;  // 2x2 wave grid of 64x64 tiles

  const int n0 = blockIdx.x * 128;
  const int m0 = blockIdx.y * 128;

  // ---- B staging (dequant) per-thread constants ----
  const int brow  = tid >> 1;   // 0..127 (row within B tile)
  const int bhalf = tid & 1;    // which 16-element half of BK
  const float s   = Bsc[n0 + brow];
  const float m8s = -8.0f * s;
  const int4* bp  = (const int4*)(Bp + (size_t)(n0 + brow) * (K / 2)) + bhalf * 2;
  u16* blds = Bs + (brow >> 4) * 512 + (2 * bhalf) * 128 + (brow & 15) * 8;

  // ---- A staging addresses (global_load_lds) ----
  // lane l covers row (l&15) of its 16-row group, kchunk (l>>4)
  const u16* ag = A + (size_t)(m0 + l16) * K + (size_t)quad * 8;
  u16* alds0 = As + (wave * 2 + 0) * 512;  // wave-uniform LDS base, group wave*2
  u16* alds1 = As + (wave * 2 + 1) * 512;  // group wave*2+1

  floatx4 acc[4][4];
#pragma unroll
  for (int i = 0; i < 4; ++i)
#pragma unroll
    for (int j = 0; j < 4; ++j)
      acc[i][j] = (floatx4){0.f, 0.f, 0.f, 0.f};

  const int KT = K / 32;
  for (int kt = 0; kt < KT; ++kt) {
    // B packed -> regs (issued before barrier: overlaps previous MFMA phase)
    int4 w0 = bp[(size_t)kt * 4 + 0];
    int4 w1 = bp[(size_t)kt * 4 + 1];

    __syncthreads();  // previous iter's fragment reads complete

    // A tile: 2 x 1KB direct global->LDS per wave
    gl_lds16(ag + (size_t)(wave * 2 + 0) * 16 * K + kt * 32, alds0);
    gl_lds16(ag + (size_t)(wave * 2 + 1) * 16 * K + kt * 32, alds1);

    // Dequant 8 words -> 16 bf16, write 2 x ds_write_b128
    int wv[8] = {w0.x, w0.y, w0.z, w0.w, w1.x, w1.y, w1.z, w1.w};
    union { u16 e[16]; uint4 q[2]; } u;
#pragma unroll
    for (int j = 0; j < 8; ++j) {
      int v = wv[j];
      float fh = fmaf((float)(v >> 4), s, m8s);   // even k (hi nibble)
      float fl = fmaf((float)(v & 15), s, m8s);   // odd k  (lo nibble)
      u.e[2 * j]     = f32_bf16_rne(fh);
      u.e[2 * j + 1] = f32_bf16_rne(fl);
    }
    *(uint4*)(blds)       = u.q[0];
    *(uint4*)(blds + 128) = u.q[1];

    __syncthreads();  // staging visible (drains global_load_lds + ds_write)

    bf16x8 af[4], bf[4];
#pragma unroll
    for (int im = 0; im < 4; ++im)
      af[im] = *(const bf16x8*)(As + (wm * 4 + im) * 512 + quad * 128 + l16 * 8);
#pragma unroll
    for (int in = 0; in < 4; ++in)
      bf[in] = *(const bf16x8*)(Bs + (wn * 4 + in) * 512 + quad * 128 + l16 * 8);

#pragma unroll
    for (int im = 0; im < 4; ++im)
#pragma unroll
      for (int in = 0; in < 4; ++in)
        acc[im][in] = __builtin_amdgcn_mfma_f32_16x16x32_bf16(af[im], bf[in], acc[im][in], 0, 0, 0);
  }

  // Epilogue: C/D layout col=lane&15, row=quad*4+r (m89/m91 verified)
#pragma unroll
  for (int im = 0; im < 4; ++im) {
#pragma unroll
    for (int r = 0; r < 4; ++r) {
      const int row = m0 + wm * 64 + im * 16 + quad * 4 + r;
#pragma unroll
      for (int in = 0; in < 4; ++in) {
        const int col = n0 + wn * 64 + in * 16 + l16;
        float v = acc[im][in][r];
        if constexpr (GELU) {
          Cb[(size_t)row * N + col] = f32_bf16_rne(gelu_tanh(v));
        } else {
          Cf[(size_t)row * N + col] = v;
        }
      }
    }
  }
}

extern "C" void kernel_launch(void* const* d_in, const int* in_sizes, int n_in,
                              void* d_out, int out_size, void* d_ws, size_t ws_size,
                              hipStream_t stream) {
  const float* x   = (const float*)d_in[0];
  const int*   f1p = (const int*)d_in[1];
  const float* f1s = (const float*)d_in[2];
  const int*   f2p = (const int*)d_in[3];
  const float* f2s = (const float*)d_in[4];
  float* out = (float*)d_out;

  // ws: x_bf16 (32 MB) + h_bf16 (128 MB)
  const size_t need = ((size_t)NTOK * D_MODEL + (size_t)NTOK * HIDDEN) * sizeof(u16);
  if (ws_size < need) return;  // fail loudly via correctness check rather than corrupt

  u16* xb = (u16*)d_ws;
  u16* h  = xb + (size_t)NTOK * D_MODEL;

  cvt_f32_bf16<<<(NTOK * D_MODEL) / 1024, 256, 0, stream>>>((const float4*)x, (ushort4*)xb);

  gemm_dq<D_MODEL, HIDDEN, true>
      <<<dim3(HIDDEN / 128, NTOK / 128), 256, 0, stream>>>(xb, f1p, f1s, h, nullptr);

  gemm_dq<HIDDEN, D_MODEL, false>
      <<<dim3(D_MODEL / 128, NTOK / 128), 256, 0, stream>>>(h, f2p, f2s, nullptr, out);
}

// Round 2
// 2463.375 us; speedup vs baseline: 1.0439x; 1.0439x over previous
//
#include <hip/hip_runtime.h>
#include <cstdint>

typedef unsigned short u16;
typedef unsigned int   u32;

#define D_MODEL 4096
#define HIDDEN  16384
#define NTOK    4096

typedef short bf16x8  __attribute__((ext_vector_type(8)));
typedef float floatx4 __attribute__((ext_vector_type(4)));

typedef __attribute__((address_space(1))) u32 gu32;
typedef __attribute__((address_space(3))) u32 lu32;

__device__ __forceinline__ void gl_lds16(const void* g, void* l) {
  __builtin_amdgcn_global_load_lds((gu32*)g, (lu32*)l, 16, 0, 0);
}

__device__ __forceinline__ u16 f32_bf16_rne(float f) {
  union { float f; u32 u; } c; c.f = f;
  u32 u = c.u;
  return (u16)((u + 0x7FFFu + ((u >> 16) & 1u)) >> 16);
}

__device__ __forceinline__ float gelu_tanh(float x) {
  // jax.nn.gelu approximate=True
  float inner = 0.7978845608028654f * fmaf(0.044715f * x * x, x, x);
  return 0.5f * x * (1.0f + tanhf(inner));
}

// x fp32 -> bf16, 4-wide.
__global__ void __launch_bounds__(256) cvt_f32_bf16(const float4* __restrict__ in,
                                                    ushort4* __restrict__ out) {
  int i = blockIdx.x * 256 + threadIdx.x;
  float4 v = in[i];
  ushort4 o;
  o.x = f32_bf16_rne(v.x);
  o.y = f32_bf16_rne(v.y);
  o.z = f32_bf16_rne(v.z);
  o.w = f32_bf16_rne(v.w);
  out[i] = o;
}

// Dequant a chunk of W rows: packed [rows, K/2] int32 (1 byte each, hi nibble = even col)
// -> bf16 [rows, K]. One thread = 4 int32 = 8 weights = one 16B store. Memory-bound.
template <int K>
__global__ void __launch_bounds__(256)
dequant_w(const int4* __restrict__ Bp, const float* __restrict__ Bsc,
          uint4* __restrict__ W, int rowOffset) {
  const int i = blockIdx.x * 256 + threadIdx.x;   // 8-weight group index within chunk
  const int row_local = i / (K / 8);
  const float s = Bsc[rowOffset + row_local];
  const float m8s = -8.0f * s;
  int4 p = Bp[(size_t)rowOffset * (K / 8) + i];
  int b[4] = {p.x, p.y, p.z, p.w};
  union { u16 e[8]; uint4 q; } u;
#pragma unroll
  for (int j = 0; j < 4; ++j) {
    u.e[2 * j]     = f32_bf16_rne(fmaf((float)(b[j] >> 4), s, m8s));
    u.e[2 * j + 1] = f32_bf16_rne(fmaf((float)(b[j] & 15), s, m8s));
  }
  W[i] = u.q;
}

// Pure bf16 NT-GEMM (m97 structure): C[M, NLD](+nbase cols) = A[M,K] * B[rows,K]^T
// BM=BN=128, BK=32, 256 threads = 4 waves of 64x64 (4x4 x mfma 16x16x32).
// Both operands staged global->LDS via global_load_lds width=16.
// LDS layout: [rowgroup g=row/16][kchunk c=k/8][row%16] 16B chunks
//   (ushort offset g*512 + c*128 + (row%16)*8); matches gl_lds lane order and is
//   2-way-conflict-free on ds_read_b128.
template <int K, int NLD, bool GELU>
__global__ void __launch_bounds__(256)
gemm_nt(const u16* __restrict__ A, const u16* __restrict__ B,
        u16* __restrict__ Cb, float* __restrict__ Cf, int nbase) {
  __shared__ __align__(16) u16 As[128 * 32];
  __shared__ __align__(16) u16 Bs[128 * 32];

  const int tid  = threadIdx.x;
  const int lane = tid & 63;
  const int wave = tid >> 6;
  const int quad = lane >> 4;
  const int l16  = lane & 15;
  const int wm = wave >> 1, wn = wave & 1;

  const int n0 = blockIdx.x * 128;   // within chunk
  const int m0 = blockIdx.y * 128;

  const u16* ag = A + (size_t)(m0 + l16) * K + (size_t)quad * 8;
  const u16* bg = B + (size_t)(n0 + l16) * K + (size_t)quad * 8;
  u16* alds0 = As + (wave * 2 + 0) * 512;
  u16* alds1 = As + (wave * 2 + 1) * 512;
  u16* blds0 = Bs + (wave * 2 + 0) * 512;
  u16* blds1 = Bs + (wave * 2 + 1) * 512;

  floatx4 acc[4][4];
#pragma unroll
  for (int i = 0; i < 4; ++i)
#pragma unroll
    for (int j = 0; j < 4; ++j)
      acc[i][j] = (floatx4){0.f, 0.f, 0.f, 0.f};

  const int KT = K / 32;
  for (int kt = 0; kt < KT; ++kt) {
    __syncthreads();  // previous iter's fragment reads complete
    gl_lds16(ag + (size_t)((wave * 2 + 0) * 16) * K + kt * 32, alds0);
    gl_lds16(ag + (size_t)((wave * 2 + 1) * 16) * K + kt * 32, alds1);
    gl_lds16(bg + (size_t)((wave * 2 + 0) * 16) * K + kt * 32, blds0);
    gl_lds16(bg + (size_t)((wave * 2 + 1) * 16) * K + kt * 32, blds1);
    __syncthreads();  // staging drained (vmcnt(0) before barrier)

    bf16x8 af[4], bf[4];
#pragma unroll
    for (int im = 0; im < 4; ++im)
      af[im] = *(const bf16x8*)(As + (wm * 4 + im) * 512 + quad * 128 + l16 * 8);
#pragma unroll
    for (int in = 0; in < 4; ++in)
      bf[in] = *(const bf16x8*)(Bs + (wn * 4 + in) * 512 + quad * 128 + l16 * 8);

#pragma unroll
    for (int im = 0; im < 4; ++im)
#pragma unroll
      for (int in = 0; in < 4; ++in)
        acc[im][in] = __builtin_amdgcn_mfma_f32_16x16x32_bf16(af[im], bf[in], acc[im][in], 0, 0, 0);
  }

  // C/D layout: col=lane&15, row=quad*4+r (m89/m91 verified)
#pragma unroll
  for (int im = 0; im < 4; ++im) {
#pragma unroll
    for (int r = 0; r < 4; ++r) {
      const int row = m0 + wm * 64 + im * 16 + quad * 4 + r;
#pragma unroll
      for (int in = 0; in < 4; ++in) {
        const int col = nbase + n0 + wn * 64 + in * 16 + l16;
        float v = acc[im][in][r];
        if constexpr (GELU) {
          Cb[(size_t)row * NLD + col] = f32_bf16_rne(gelu_tanh(v));
        } else {
          Cf[(size_t)row * NLD + col] = v;
        }
      }
    }
  }
}

// ---------------- Fallback: round-1 fused dequant GEMM (ws too small) ------------
template <int K, int N, bool GELU>
__global__ void __launch_bounds__(256)
gemm_dq(const u16* __restrict__ A, const int* __restrict__ Bp,
        const float* __restrict__ Bsc, u16* __restrict__ Cb, float* __restrict__ Cf) {
  __shared__ __align__(16) u16 As[128 * 32];
  __shared__ __align__(16) u16 Bs[128 * 32];

  const int tid  = threadIdx.x;
  const int lane = tid & 63;
  const int wave = tid >> 6;
  const int quad = lane >> 4;
  const int l16  = lane & 15;
  const int wm = wave >> 1, wn = wave & 1;

  const int n0 = blockIdx.x * 128;
  const int m0 = blockIdx.y * 128;

  const int brow  = tid >> 1;
  const int bhalf = tid & 1;
  const float s   = Bsc[n0 + brow];
  const float m8s = -8.0f * s;
  const int4* bp  = (const int4*)(Bp + (size_t)(n0 + brow) * (K / 2)) + bhalf * 2;
  u16* blds = Bs + (brow >> 4) * 512 + (2 * bhalf) * 128 + (brow & 15) * 8;

  const u16* ag = A + (size_t)(m0 + l16) * K + (size_t)quad * 8;
  u16* alds0 = As + (wave * 2 + 0) * 512;
  u16* alds1 = As + (wave * 2 + 1) * 512;

  floatx4 acc[4][4];
#pragma unroll
  for (int i = 0; i < 4; ++i)
#pragma unroll
    for (int j = 0; j < 4; ++j)
      acc[i][j] = (floatx4){0.f, 0.f, 0.f, 0.f};

  const int KT = K / 32;
  for (int kt = 0; kt < KT; ++kt) {
    int4 w0 = bp[(size_t)kt * 4 + 0];
    int4 w1 = bp[(size_t)kt * 4 + 1];
    __syncthreads();
    gl_lds16(ag + (size_t)(wave * 2 + 0) * 16 * K + kt * 32, alds0);
    gl_lds16(ag + (size_t)(wave * 2 + 1) * 16 * K + kt * 32, alds1);
    int wv[8] = {w0.x, w0.y, w0.z, w0.w, w1.x, w1.y, w1.z, w1.w};
    union { u16 e[16]; uint4 q[2]; } u;
#pragma unroll
    for (int j = 0; j < 8; ++j) {
      int v = wv[j];
      u.e[2 * j]     = f32_bf16_rne(fmaf((float)(v >> 4), s, m8s));
      u.e[2 * j + 1] = f32_bf16_rne(fmaf((float)(v & 15), s, m8s));
    }
    *(uint4*)(blds)       = u.q[0];
    *(uint4*)(blds + 128) = u.q[1];
    __syncthreads();

    bf16x8 af[4], bf[4];
#pragma unroll
    for (int im = 0; im < 4; ++im)
      af[im] = *(const bf16x8*)(As + (wm * 4 + im) * 512 + quad * 128 + l16 * 8);
#pragma unroll
    for (int in = 0; in < 4; ++in)
      bf[in] = *(const bf16x8*)(Bs + (wn * 4 + in) * 512 + quad * 128 + l16 * 8);
#pragma unroll
    for (int im = 0; im < 4; ++im)
#pragma unroll
      for (int in = 0; in < 4; ++in)
        acc[im][in] = __builtin_amdgcn_mfma_f32_16x16x32_bf16(af[im], bf[in], acc[im][in], 0, 0, 0);
  }

#pragma unroll
  for (int im = 0; im < 4; ++im) {
#pragma unroll
    for (int r = 0; r < 4; ++r) {
      const int row = m0 + wm * 64 + im * 16 + quad * 4 + r;
#pragma unroll
      for (int in = 0; in < 4; ++in) {
        const int col = n0 + wn * 64 + in * 16 + l16;
        float v = acc[im][in][r];
        if constexpr (GELU) {
          Cb[(size_t)row * N + col] = f32_bf16_rne(gelu_tanh(v));
        } else {
          Cf[(size_t)row * N + col] = v;
        }
      }
    }
  }
}

extern "C" void kernel_launch(void* const* d_in, const int* in_sizes, int n_in,
                              void* d_out, int out_size, void* d_ws, size_t ws_size,
                              hipStream_t stream) {
  const float* x   = (const float*)d_in[0];
  const int*   f1p = (const int*)d_in[1];
  const float* f1s = (const float*)d_in[2];
  const int*   f2p = (const int*)d_in[3];
  const float* f2s = (const float*)d_in[4];
  float* out = (float*)d_out;

  const size_t xb_bytes = (size_t)NTOK * D_MODEL * 2;   // 32 MiB
  const size_t h_bytes  = (size_t)NTOK * HIDDEN * 2;    // 128 MiB
  const size_t base     = xb_bytes + h_bytes;
  if (ws_size < base) return;

  u16* xb = (u16*)d_ws;
  u16* h  = xb + (size_t)NTOK * D_MODEL;

  cvt_f32_bf16<<<(NTOK * D_MODEL) / 1024, 256, 0, stream>>>((const float4*)x, (ushort4*)xb);

  // Pick W1 chunk rows NC1 (multiple of 128); W2 chunk NC2 = NC1/4 uses the same bytes.
  const size_t avail = ws_size - base;
  int NC1 = 0;
  for (int c = HIDDEN; c >= 512; c >>= 1)
    if ((size_t)c * D_MODEL * 2 <= avail) { NC1 = c; break; }

  if (NC1 == 0) {
    // Fallback: fused dequant (round-1 proven path)
    gemm_dq<D_MODEL, HIDDEN, true>
        <<<dim3(HIDDEN / 128, NTOK / 128), 256, 0, stream>>>(xb, f1p, f1s, h, nullptr);
    gemm_dq<HIDDEN, D_MODEL, false>
        <<<dim3(D_MODEL / 128, NTOK / 128), 256, 0, stream>>>(h, f2p, f2s, nullptr, out);
    return;
  }

  u16* Wbuf = h + (size_t)NTOK * HIDDEN;
  const int NC2 = NC1 / 4;                 // same buffer bytes: NC1*D_MODEL == NC2*HIDDEN

  // GEMM1: h = gelu(x @ W1^T), chunked over W1 rows (= h columns)
  for (int r = 0; r < HIDDEN; r += NC1) {
    dequant_w<D_MODEL><<<(NC1 * (D_MODEL / 8)) / 256, 256, 0, stream>>>(
        (const int4*)f1p, f1s, (uint4*)Wbuf, r);
    gemm_nt<D_MODEL, HIDDEN, true>
        <<<dim3(NC1 / 128, NTOK / 128), 256, 0, stream>>>(xb, Wbuf, h, nullptr, r);
  }

  // GEMM2: out = h @ W2^T, chunked over W2 rows (= out columns)
  for (int r = 0; r < D_MODEL; r += NC2) {
    dequant_w<HIDDEN><<<(NC2 * (HIDDEN / 8)) / 256, 256, 0, stream>>>(
        (const int4*)f2p, f2s, (uint4*)Wbuf, r);
    gemm_nt<HIDDEN, D_MODEL, false>
        <<<dim3(NC2 / 128, NTOK / 128), 256, 0, stream>>>(h, Wbuf, nullptr, out, r);
  }
}